// Round 7
// baseline (5549.332 us; speedup 1.0000x reference)
//
#include <hip/hip_runtime.h>
#include <math.h>

// OptNet batched QP IPM solver — Round 13: 3 blocks/CU + bank-despread.
// R12 confirmed residency is the lever (LDS 80K->56K: occ 24->45%, 2456->
// 1991us). This round: LDS 56832 -> 50752 B so THREE blocks co-reside
// (3x50752=152KB <= 160KB), plus a chunk-permutation fixing the 4-way LDS
// bank conflicts R12 introduced (1.55e8 conflict cycles):
//  * t1 stride 130 -> 128; all steady-state vectors (s,z,rz,dsa,dza,u12,dd,
//    H,Y,x,rxv,dxa) moved into the dead V_Q region pool[2304,3648). Only
//    t/scalbuf/scal stay separate (live during setup under V_Q). Q-path's
//    diag stash uses t (not Y); dd=1 init moved post-t1.
//  * pch(c)=((c&1)<<4)|(c>>1): float4-chunk c of each 128-float row (t1 and
//    sweep panels) stored at position pch(c). Lane tc reads chunks 2tc,2tc+1
//    at positions tc*4 and 64+tc*4 -> 16 lanes span all 32 banks (2-way =
//    free) instead of half (4-way). Same mapping on write+read; pv/back-sub
//    go through pch(tr). Values bit-identical.
//  * __launch_bounds__(512,6) -> 3 blocks/CU (24 waves); VGPR was 64.

#define NT 512
#define T1_O 4352    // t1 = V_Q^T G^T, 64 x 128 at stride 128, chunk-permuted
#define GP_O 2048    // g1 / rx split-k partials (256 floats)
#define QP_O 4352    // Q-path chol panel / trtri Vd scratch (pre-t1)

// steady-state vectors inside the dead V_Q region [2304, 3648)
#define SM_S   (sm.pool + 2304)
#define SM_Z   (sm.pool + 2432)
#define SM_RZ  (sm.pool + 2560)
#define SM_DSA (sm.pool + 2688)
#define SM_DZA (sm.pool + 2816)
#define SM_U12 (sm.pool + 2944)
#define SM_DD  (sm.pool + 3072)
#define SM_H   (sm.pool + 3200)
#define SM_Y   (sm.pool + 3328)
#define SM_X   (sm.pool + 3456)
#define SM_RXV (sm.pool + 3520)
#define SM_DXA (sm.pool + 3584)

struct __align__(16) Smem {
  float pool[12544];  // 50176 B: V_Q/panels/partials/vectors + t1
  float t[64];        // setup: Q-path diag stash, then w = V_Q^T a / Qinv rx
  float scalbuf[64];  // Q-path: [0,16) | sweep: [16,62)
  float scal[16];
};
static_assert(sizeof(Smem) <= 52000, "LDS must allow 3 blocks/CU");

enum { SC_H1 = 2, SC_U11I = 4, SC_RY = 5, SC_MU = 6,
       SC_MUSIG = 8, SC_Y = 9, SC_DYA = 10, SC_WY = 11 };

__device__ __forceinline__ float wred_sum(float v) {
#pragma unroll
  for (int off = 32; off > 0; off >>= 1) v += __shfl_down(v, off);
  return v;
}
__device__ __forceinline__ float wred_min(float v) {
#pragma unroll
  for (int off = 32; off > 0; off >>= 1) v = fminf(v, __shfl_down(v, off));
  return v;
}
__device__ __forceinline__ float step_val(float v, float dv) {
  float a = -v / dv;
  return (a > 0.0f) ? a : __builtin_inff();  // NaN -> inf (matches ref)
}
__device__ __forceinline__ constexpr int pk16(int i) {  // packed 16x16 upper row start
  return i * 16 - ((i * (i - 1)) >> 1);
}
// chunk permutation for 128-float rows: chunk c (float4 index, 0..31) stored
// at position pch(c). Bijective; lane tc's chunks {2tc,2tc+1} -> {tc, 16+tc}
// -> float offsets {4tc, 64+4tc}: 16 lanes cover all 32 banks (2-way).
__device__ __forceinline__ constexpr int pch(int c) {
  return ((c & 1) << 4) | (c >> 1);
}

// ======================= Q-path (64x64) machinery ==========================
// Panels/Vd at pool[QP_O..) (free until t1 exists). Diag stash in sm.t.

template<int RW>
__device__ __forceinline__ void elim_publish(Smem& sm, float* pan, float (&Wt)[4][8],
                                             int q, int tc) {
  const int tcd = q >> 1;
  const int co = (q & 1) << 2;
  float L10 = 0, L20 = 0, L30 = 0, L21 = 0, L31 = 0, L32 = 0;
  float id0 = 0, id1 = 0, id2 = 0, id3 = 0;
  if (tc == tcd) {
    float D[4][4];
#pragma unroll
    for (int m = 0; m < 4; ++m)
#pragma unroll
      for (int c = 0; c < 4; ++c) D[m][c] = Wt[m][co + c];
    id0 = 1.0f / D[0][0];
    L10 = D[0][1] * id0; L20 = D[0][2] * id0; L30 = D[0][3] * id0;
#pragma unroll
    for (int c = 0; c < 4; ++c) {
      D[1][c] -= L10 * D[0][c]; D[2][c] -= L20 * D[0][c]; D[3][c] -= L30 * D[0][c];
    }
    id1 = 1.0f / D[1][1];
    L21 = D[1][2] * id1; L31 = D[1][3] * id1;
#pragma unroll
    for (int c = 0; c < 4; ++c) { D[2][c] -= L21 * D[1][c]; D[3][c] -= L31 * D[1][c]; }
    id2 = 1.0f / D[2][2];
    L32 = D[2][3] * id2;
#pragma unroll
    for (int c = 0; c < 4; ++c) D[3][c] -= L32 * D[2][c];
    id3 = 1.0f / D[3][3];
  }
  const int src = ((q & 3) << 4) + tcd;
  L10 = __shfl(L10, src); L20 = __shfl(L20, src); L30 = __shfl(L30, src);
  L21 = __shfl(L21, src); L31 = __shfl(L31, src); L32 = __shfl(L32, src);
#pragma unroll
  for (int c = 0; c < 8; ++c) {
    Wt[1][c] = fmaf(-L10, Wt[0][c], Wt[1][c]);
    Wt[2][c] = fmaf(-L20, Wt[0][c], Wt[2][c]);
    Wt[2][c] = fmaf(-L21, Wt[1][c], Wt[2][c]);
    Wt[3][c] = fmaf(-L30, Wt[0][c], Wt[3][c]);
    Wt[3][c] = fmaf(-L31, Wt[1][c], Wt[3][c]);
    Wt[3][c] = fmaf(-L32, Wt[2][c], Wt[3][c]);
  }
  const int pb = (q >> 1) & 1;
  float* pp = pan + pb * (8 * RW) + (q & 1) * (4 * RW);
  const int j0 = tc << 3;
#pragma unroll
  for (int m = 0; m < 4; ++m) {
    *(float4*)&pp[m * RW + j0]     = make_float4(Wt[m][0], Wt[m][1], Wt[m][2], Wt[m][3]);
    *(float4*)&pp[m * RW + j0 + 4] = make_float4(Wt[m][4], Wt[m][5], Wt[m][6], Wt[m][7]);
  }
  if (tc == tcd) {
    float* sb = sm.scalbuf + pb * 8 + ((q & 1) << 2);
    sb[0] = id0; sb[1] = id1; sb[2] = id2; sb[3] = id3;
    sm.t[(q << 2) + 0] = id0; sm.t[(q << 2) + 1] = id1;  // diag stash (read by write_U)
    sm.t[(q << 2) + 2] = id2; sm.t[(q << 2) + 3] = id3;
  }
}

template<int RW>
__device__ __forceinline__ void apply_panel4(Smem& sm, float* pan, float (&Wt)[4][8],
                                             int pb, int half, int i0, int j0) {
  const float* pp = pan + pb * (8 * RW) + half * (4 * RW);
  const float* sb = sm.scalbuf + pb * 8 + (half << 2);
#pragma unroll 1
  for (int mm = 0; mm < 4; ++mm) {
    const float idm = sb[mm];
    const float4 pv  = *(const float4*)&pp[mm * RW + i0];
    const float4 pj0 = *(const float4*)&pp[mm * RW + j0];
    const float4 pj1 = *(const float4*)&pp[mm * RW + j0 + 4];
    const float um0 = pv.x * idm, um1 = pv.y * idm;
    const float um2 = pv.z * idm, um3 = pv.w * idm;
    const float pjv[8] = {pj0.x, pj0.y, pj0.z, pj0.w, pj1.x, pj1.y, pj1.z, pj1.w};
#pragma unroll
    for (int c = 0; c < 8; ++c) {
      Wt[0][c] = fmaf(-um0, pjv[c], Wt[0][c]);
      Wt[1][c] = fmaf(-um1, pjv[c], Wt[1][c]);
      Wt[2][c] = fmaf(-um2, pjv[c], Wt[2][c]);
      Wt[3][c] = fmaf(-um3, pjv[c], Wt[3][c]);
    }
  }
}

template<int N, int RW, int ST>
__device__ void chol_rank8(Smem& sm, float* pan, float (&Wt)[4][8], int act, int tid) {
  const int tr = tid >> 4, tc = tid & 15;
  const int i0 = tr << 2, j0 = tc << 3;
  constexpr int NP = N / 8;
#pragma unroll 1
  for (int P = 0; P < NP; ++P) {
    const int pb = P & 1;
    if (P > 0 && act && tr >= 2 * P) {
      apply_panel4<RW>(sm, pan, Wt, pb ^ 1, 0, i0, j0);
      apply_panel4<RW>(sm, pan, Wt, pb ^ 1, 1, i0, j0);
    }
    if ((tid >> 6) == (P >> 1)) {
      if (act && tr == 2 * P) elim_publish<RW>(sm, pan, Wt, 2 * P, tc);
      __threadfence_block();
      if (act && tr == 2 * P + 1) {
        apply_panel4<RW>(sm, pan, Wt, pb, 0, i0, j0);
        elim_publish<RW>(sm, pan, Wt, 2 * P + 1, tc);
      }
    }
    __syncthreads();
  }
}

template<int ST>
__device__ __forceinline__ void write_U(Smem& sm, float (&Wt)[4][8], int act,
                                        int i0, int j0) {
  if (act && j0 + 7 >= i0) {
    float sqv[4];
#pragma unroll
    for (int m = 0; m < 4; ++m) sqv[m] = sqrtf(sm.t[i0 + m]);  // diag stash
    if (j0 >= i0 + 3) {
#pragma unroll
      for (int m = 0; m < 4; ++m)
#pragma unroll
        for (int qq = 0; qq < 4; ++qq)
          *(float2*)&sm.pool[(i0 + m) * ST + j0 + 2 * qq] =
              make_float2(Wt[m][2 * qq] * sqv[m], Wt[m][2 * qq + 1] * sqv[m]);
    } else {
#pragma unroll
      for (int m = 0; m < 4; ++m) {
        const int i = i0 + m;
#pragma unroll
        for (int c = 0; c < 8; ++c) {
          const int j = j0 + c;
          if (j >= i) sm.pool[i * ST + j] = Wt[m][c] * sqv[m];
        }
      }
    }
  }
}

template<int N, int ST>
__device__ void trtri_fast(Smem& sm, float* vd, int tid) {
  constexpr int NB = N >> 4;
  if (tid < NB * 16) {
    const int blk = tid >> 4, c = tid & 15;
    const float* D = sm.pool + (blk << 4) * ST + (blk << 4);
    float vv[16];
#pragma unroll
    for (int i = 15; i >= 0; --i) {
      float acc = 0.0f;
      for (int k = i + 1; k < 16; ++k) acc += D[i * ST + k] * vv[k];
      const float di = D[i * ST + i];
      const float val = (i == c) ? (1.0f / di) : (-acc / di);
      vv[i] = (i <= c) ? val : 0.0f;
    }
#pragma unroll
    for (int i = 0; i < 16; ++i)
      if (i <= c) vd[blk * 136 + pk16(i) + (c - i)] = vv[i];
  }
  __syncthreads();
  constexpr int NROWS = 16 * (NB * (NB - 1) / 2);
  if (tid < NROWS) {
    int J = 1, base = 0;
    while (base + 16 * J <= tid) { base += 16 * J; ++J; }
    const int k = tid - base, Jb = J << 4;
    float u[16], o[16];
    float2* wr = (float2*)&sm.pool[k * ST + Jb];
#pragma unroll
    for (int q = 0; q < 8; ++q) { const float2 v = wr[q]; u[2*q] = v.x; u[2*q+1] = v.y; }
    const float* vdj = vd + J * 136;
#pragma unroll
    for (int c = 0; c < 16; ++c) {
      float acc = 0.0f;
#pragma unroll
      for (int jj = 0; jj <= c; ++jj) acc += u[jj] * vdj[pk16(jj) + (c - jj)];
      o[c] = acc;
    }
#pragma unroll
    for (int q = 0; q < 8; ++q) wr[q] = make_float2(o[2*q], o[2*q+1]);
  } else {
    for (int idx = tid - NROWS; idx < 256; idx += NT - NROWS) {
      const int r = idx >> 4, c2 = idx & 15;
      if (c2 >= r) sm.pool[r * ST + c2] = vd[pk16(r) + (c2 - r)];
    }
  }
  for (int J = 1; J < NB; ++J) {
    __syncthreads();
    const int Jb = J << 4;
    const int nStrip = Jb << 2;
    float acc[4] = {0.0f, 0.0f, 0.0f, 0.0f};
    int wi = 0, wc = 0;
    if (tid < nStrip) {
      wi = tid >> 2; wc = (tid & 3) << 2;
      for (int k = wi; k < Jb; ++k) {
        const float v = sm.pool[wi * ST + k];
        const float2 u0 = *(const float2*)&sm.pool[k * ST + Jb + wc];
        const float2 u1 = *(const float2*)&sm.pool[k * ST + Jb + wc + 2];
        acc[0] = fmaf(v, u0.x, acc[0]); acc[1] = fmaf(v, u0.y, acc[1]);
        acc[2] = fmaf(v, u1.x, acc[2]); acc[3] = fmaf(v, u1.y, acc[3]);
      }
      acc[0] = -acc[0]; acc[1] = -acc[1]; acc[2] = -acc[2]; acc[3] = -acc[3];
    } else if (tid < nStrip + 64) {
      const int l = tid - nStrip;
      const int r = l >> 2; wi = Jb + r; wc = (l & 3) << 2;
      const float* vp = vd + J * 136 + pk16(r) - r;
#pragma unroll
      for (int q = 0; q < 4; ++q) {
        const int c = wc + q;
        acc[q] = (c >= r) ? vp[c] : 0.0f;
      }
    }
    __syncthreads();
    if (tid < nStrip) {
      *(float2*)&sm.pool[wi * ST + Jb + wc]     = make_float2(acc[0], acc[1]);
      *(float2*)&sm.pool[wi * ST + Jb + wc + 2] = make_float2(acc[2], acc[3]);
    } else if (tid < nStrip + 64) {
      const int r = wi - Jb;
#pragma unroll
      for (int q = 0; q < 4; ++q)
        if (wc + q >= r) sm.pool[wi * ST + Jb + wc + q] = acc[q];
    }
  }
  __syncthreads();
}

// ======================= 128-factor: symmetric SWEEP (register-resident) ===
// Panels at pool[0,2048), rows chunk-permuted via pch(). After the sweep,
// Wt = -M^{-1} (full square tile per thread), never written to LDS.

__device__ __forceinline__ void elim_sweep(Smem& sm, float (&Wt)[4][8],
                                           int q, int tc) {
  const int tcd = q >> 1;
  const int co = (q & 1) << 2;
  float L10 = 0, L20 = 0, L30 = 0, L21 = 0, L31 = 0, L32 = 0;
  float id0 = 0, id1 = 0, id2 = 0, id3 = 0;
  if (tc == tcd) {
    float D[4][4];
#pragma unroll
    for (int m = 0; m < 4; ++m)
#pragma unroll
      for (int c = 0; c < 4; ++c) D[m][c] = Wt[m][co + c];
    id0 = 1.0f / D[0][0];
    L10 = D[0][1] * id0; L20 = D[0][2] * id0; L30 = D[0][3] * id0;
#pragma unroll
    for (int c = 0; c < 4; ++c) {
      D[1][c] -= L10 * D[0][c]; D[2][c] -= L20 * D[0][c]; D[3][c] -= L30 * D[0][c];
    }
    id1 = 1.0f / D[1][1];
    L21 = D[1][2] * id1; L31 = D[1][3] * id1;
#pragma unroll
    for (int c = 0; c < 4; ++c) { D[2][c] -= L21 * D[1][c]; D[3][c] -= L31 * D[1][c]; }
    id2 = 1.0f / D[2][2];
    L32 = D[2][3] * id2;
#pragma unroll
    for (int c = 0; c < 4; ++c) D[3][c] -= L32 * D[2][c];
    id3 = 1.0f / D[3][3];
  }
  const int src = ((q & 3) << 4) + tcd;
  L10 = __shfl(L10, src); L20 = __shfl(L20, src); L30 = __shfl(L30, src);
  L21 = __shfl(L21, src); L31 = __shfl(L31, src); L32 = __shfl(L32, src);
  id0 = __shfl(id0, src); id1 = __shfl(id1, src);
  id2 = __shfl(id2, src); id3 = __shfl(id3, src);
#pragma unroll
  for (int c = 0; c < 8; ++c) {  // own rows -> F_raw = L^{-1} * rows
    Wt[1][c] = fmaf(-L10, Wt[0][c], Wt[1][c]);
    Wt[2][c] = fmaf(-L20, Wt[0][c], Wt[2][c]);
    Wt[2][c] = fmaf(-L21, Wt[1][c], Wt[2][c]);
    Wt[3][c] = fmaf(-L30, Wt[0][c], Wt[3][c]);
    Wt[3][c] = fmaf(-L31, Wt[1][c], Wt[3][c]);
    Wt[3][c] = fmaf(-L32, Wt[2][c], Wt[3][c]);
  }
  const int pb = (q >> 1) & 1;
  float* pp = sm.pool + pb * 1024 + (q & 1) * 512;
  // publish F_raw: chunk 2tc -> pos tc*4, chunk 2tc+1 -> pos 64+tc*4 (pch)
  const int c0 = tc << 2;
#pragma unroll
  for (int m = 0; m < 4; ++m) {
    *(float4*)&pp[m * 128 + c0]      = make_float4(Wt[m][0], Wt[m][1], Wt[m][2], Wt[m][3]);
    *(float4*)&pp[m * 128 + 64 + c0] = make_float4(Wt[m][4], Wt[m][5], Wt[m][6], Wt[m][7]);
  }
  if (tc == tcd) {
    float* sb = sm.scalbuf + 16 + pb * 24 + (q & 1) * 12;
    sb[0] = id0; sb[1] = id1; sb[2] = id2; sb[3] = id3;
    sb[4] = L10; sb[5] = L20; sb[6] = L30; sb[7] = L21; sb[8] = L31; sb[9] = L32;
  }
  // own rows -> P^{-1}B = L^{-T} D^{-1} F (back-substitution, per column)
#pragma unroll
  for (int c = 0; c < 8; ++c) {
    const float t3 = id3 * Wt[3][c];
    const float t2 = id2 * Wt[2][c] - L32 * t3;
    const float t1v = id1 * Wt[1][c] - L21 * t2 - L31 * t3;
    const float t0 = id0 * Wt[0][c] - L10 * t1v - L20 * t2 - L30 * t3;
    Wt[0][c] = t0; Wt[1][c] = t1v; Wt[2][c] = t2; Wt[3][c] = t3;
  }
  if (tc == tcd) {  // pivot 4x4 <- -P^{-1} = -(L^{-1})^T D^{-1} L^{-1}
    const float m10 = -L10, m21 = -L21, m32 = -L32;
    const float m20 = -L20 + L21 * L10;
    const float m31 = -L31 + L32 * L21;
    const float m30 = -L30 + L31 * L10 + L32 * L20 - L32 * L21 * L10;
    const float P00 = id0 + id1*m10*m10 + id2*m20*m20 + id3*m30*m30;
    const float P01 = id1*m10 + id2*m20*m21 + id3*m30*m31;
    const float P02 = id2*m20 + id3*m30*m32;
    const float P03 = id3*m30;
    const float P11 = id1 + id2*m21*m21 + id3*m31*m31;
    const float P12 = id2*m21 + id3*m31*m32;
    const float P13 = id3*m31;
    const float P22 = id2 + id3*m32*m32;
    const float P23 = id3*m32;
    const float P33 = id3;
    Wt[0][co+0] = -P00; Wt[0][co+1] = -P01; Wt[0][co+2] = -P02; Wt[0][co+3] = -P03;
    Wt[1][co+0] = -P01; Wt[1][co+1] = -P11; Wt[1][co+2] = -P12; Wt[1][co+3] = -P13;
    Wt[2][co+0] = -P02; Wt[2][co+1] = -P12; Wt[2][co+2] = -P22; Wt[2][co+3] = -P23;
    Wt[3][co+0] = -P03; Wt[3][co+1] = -P13; Wt[3][co+2] = -P23; Wt[3][co+3] = -P33;
  }
}

__device__ __forceinline__ void apply_sweep(Smem& sm, float (&Wt)[4][8],
                                            int q, int i0, int j0, int tr, int tc,
                                            int skip_partner) {
  if (tr == q) return;  // own panel: rows already replaced at elim time
  if (skip_partner && !(q & 1) && tr == q + 1) return;
  const int pb = (q >> 1) & 1;
  const float* pp = sm.pool + pb * 1024 + (q & 1) * 512;
  const float* sb = sm.scalbuf + 16 + pb * 24 + (q & 1) * 12;
  const int c0 = tc << 2;                  // pch(2tc)*4
  const int pvo = pch(tr) << 2;            // chunk tr position (cols i0..i0+3)
#pragma unroll 1
  for (int mm = 0; mm < 4; ++mm) {
    const float idm = sb[mm];
    const float4 pv  = *(const float4*)&pp[mm * 128 + pvo];
    const float4 pj0 = *(const float4*)&pp[mm * 128 + c0];
    const float4 pj1 = *(const float4*)&pp[mm * 128 + 64 + c0];
    const float um0 = pv.x * idm, um1 = pv.y * idm;
    const float um2 = pv.z * idm, um3 = pv.w * idm;
    const float pjv[8] = {pj0.x, pj0.y, pj0.z, pj0.w, pj1.x, pj1.y, pj1.z, pj1.w};
#pragma unroll
    for (int c = 0; c < 8; ++c) {
      Wt[0][c] = fmaf(-um0, pjv[c], Wt[0][c]);
      Wt[1][c] = fmaf(-um1, pjv[c], Wt[1][c]);
      Wt[2][c] = fmaf(-um2, pjv[c], Wt[2][c]);
      Wt[3][c] = fmaf(-um3, pjv[c], Wt[3][c]);
    }
  }
  if (tc == (q >> 1)) {  // pivot-column cells: (P^{-1}B)[:, i] via back-sub
    const int co = (q & 1) << 2;
    const float id0 = sb[0], id1 = sb[1], id2 = sb[2], id3 = sb[3];
    const float L10 = sb[4], L20 = sb[5], L30 = sb[6];
    const float L21 = sb[7], L31 = sb[8], L32 = sb[9];
#pragma unroll
    for (int r = 0; r < 4; ++r) {
      const float f0 = pp[0 * 128 + pvo + r];
      const float f1 = pp[1 * 128 + pvo + r];
      const float f2 = pp[2 * 128 + pvo + r];
      const float f3 = pp[3 * 128 + pvo + r];
      const float t3 = id3 * f3;
      const float t2 = id2 * f2 - L32 * t3;
      const float t1v = id1 * f1 - L21 * t2 - L31 * t3;
      const float t0 = id0 * f0 - L10 * t1v - L20 * t2 - L30 * t3;
      Wt[r][co+0] = t0; Wt[r][co+1] = t1v; Wt[r][co+2] = t2; Wt[r][co+3] = t3;
    }
  }
}

__device__ void sweep128(Smem& sm, float (&Wt)[4][8], int tid) {
  const int tr = tid >> 4, tc = tid & 15;
  const int i0 = tr << 2, j0 = tc << 3;
#pragma unroll 1
  for (int P = 0; P < 16; ++P) {
    if (P > 0) {
      apply_sweep(sm, Wt, 2 * P - 2, i0, j0, tr, tc, 1);
      apply_sweep(sm, Wt, 2 * P - 1, i0, j0, tr, tc, 1);
    }
    if ((tid >> 6) == (P >> 1)) {
      if (tr == 2 * P) elim_sweep(sm, Wt, 2 * P, tc);
      __threadfence_block();
      if (tr == 2 * P + 1) {
        apply_sweep(sm, Wt, 2 * P, i0, j0, tr, tc, 0);
        elim_sweep(sm, Wt, 2 * P + 1, tc);
      }
    }
    __syncthreads();
  }
  apply_sweep(sm, Wt, 30, i0, j0, tr, tc, 1);
  apply_sweep(sm, Wt, 31, i0, j0, tr, tc, 1);
}

// ---- rebuild S = t1^T t1 - u12 u12^T + diag(d + eps) into registers.
// t1 rows are chunk-permuted; same fma order every factor. ----
__device__ void rebuild_S(Smem& sm, float (&Wt)[4][8], int init, int tid) {
  const int tr = tid >> 4, tc = tid & 15;
  const int i0 = tr << 2, j0 = tc << 3;
  const int c0 = tc << 2;          // pch(2tc)*4
  const int pvo = pch(tr) << 2;    // chunk tr position
#pragma unroll
  for (int m = 0; m < 4; ++m)
#pragma unroll
    for (int c = 0; c < 8; ++c) Wt[m][c] = 0.0f;
#pragma unroll 2
  for (int k = 0; k < 64; ++k) {
    const float* row = sm.pool + T1_O + k * 128;
    const float4 a  = *(const float4*)&row[pvo];
    const float4 b0 = *(const float4*)&row[c0];
    const float4 b1 = *(const float4*)&row[64 + c0];
    const float av[4] = {a.x, a.y, a.z, a.w};
    const float bv[8] = {b0.x, b0.y, b0.z, b0.w, b1.x, b1.y, b1.z, b1.w};
#pragma unroll
    for (int m = 0; m < 4; ++m)
#pragma unroll
      for (int c = 0; c < 8; ++c) Wt[m][c] = fmaf(av[m], bv[c], Wt[m][c]);
  }
#pragma unroll
  for (int m = 0; m < 4; ++m) {
    const float ui = SM_U12[i0 + m];
#pragma unroll
    for (int c = 0; c < 8; ++c) Wt[m][c] -= ui * SM_U12[j0 + c];
  }
#pragma unroll
  for (int m = 0; m < 4; ++m) {
    const int i = i0 + m;
    if (i >= j0 && i < j0 + 8) {
      const int c = i - j0;
      const float dval = init ? 1.0f : SM_S[i] / SM_Z[i];
      Wt[m][c] = Wt[m][c] + dval + 1e-6f;
    }
  }
}

// ---- KKT solve from register-resident -M^{-1} (Wt). has_rx=0 (corrector):
// t & H phases skipped — H, SC_H1 pre-filled by the caller. ----
__device__ void solve_kkt(Smem& sm, const float (&Wt)[4][8], const float* qreg,
                          const float* Gb, const float* Ab,
                          int has_rx, const float* rx, const float* rs,
                          int has_rz, const float* rz, float ry,
                          float* dx_t, float* ds_t, float* dz_t, int dy_slot,
                          int accum, int tid) {
  const float u11i = sm.scal[SC_U11I];
  const int o8 = tid >> 3, seg = tid & 7;
  const int tr = tid >> 4, tc = tid & 15;
  const int i0 = tr << 2, j0 = tc << 3;
  if (has_rx) {
    {  // t = Qinv rx via register Qi + 8-lane shfl reduce
      float acc = 0.0f;
#pragma unroll
      for (int c = 0; c < 8; ++c) acc += qreg[c] * rx[seg * 8 + c];
      acc += __shfl_down(acc, 4); acc += __shfl_down(acc, 2); acc += __shfl_down(acc, 1);
      if (seg == 0) sm.t[o8] = acc;
    }
    __syncthreads();
    {  // H = G t + rs/d - rz  (float4 row dots) + fused H1 = a.t - ry
      const int i = tid >> 2, q = tid & 3;
      float acc = 0.0f;
      const float* gr = Gb + (i << 6) + (q << 4);
#pragma unroll
      for (int kk = 0; kk < 16; kk += 4) {
        const float4 g4 = *(const float4*)(gr + kk);
        const float4 t4 = *(const float4*)&sm.t[(q << 4) + kk];
        acc += g4.x * t4.x + g4.y * t4.y + g4.z * t4.z + g4.w * t4.w;
      }
      float h1v = (tid < 64) ? Ab[tid] * sm.t[tid] : 0.0f;
      h1v = wred_sum(h1v);  // meaningful in wave 0 only
      acc += __shfl_down(acc, 2); acc += __shfl_down(acc, 1);
      if (q == 0) {
        if (rs) acc += rs[i] / SM_DD[i];
        if (has_rz) acc -= rz[i];
        SM_H[i] = acc;
      }
      if (tid == 0) sm.scal[SC_H1] = h1v - ry;
    }
    __syncthreads();
  }
  const float y1 = sm.scal[SC_H1] * u11i;
  {  // wz = Wt.(H - u12 y1), row-reduce over the 16-lane tc group -> Y
    float v[8];
#pragma unroll
    for (int c = 0; c < 8; ++c) v[c] = SM_H[j0 + c] - SM_U12[j0 + c] * y1;
#pragma unroll
    for (int m = 0; m < 4; ++m) {
      float p = 0.0f;
#pragma unroll
      for (int c = 0; c < 8; ++c) p = fmaf(Wt[m][c], v[c], p);
      p += __shfl_down(p, 8); p += __shfl_down(p, 4);
      p += __shfl_down(p, 2); p += __shfl_down(p, 1);
      if (tc == 0) SM_Y[i0 + m] = p;
    }
  }
  __syncthreads();
  // FUSED: g1 partials (tid<256) | ds,dz (256..384) | w_y (wave 6) — read Y
  if (tid < 256) {
    const int o = tid & 63, p = tid >> 6;
    float acc = 0.0f;
    for (int i = (p << 5); i < (p << 5) + 32; ++i)
      acc -= Gb[(i << 6) + o] * SM_Y[i];
    sm.pool[GP_O + (p << 6) + o] = acc;
  } else if (tid < 384) {
    const int i = tid - 256;
    const float wzv = SM_Y[i];
    const float r = rs ? rs[i] : 0.0f;
    const float dsv = (-r - wzv) / SM_DD[i];
    if (accum) { ds_t[i] += dsv; dz_t[i] += wzv; }
    else       { ds_t[i] = dsv;  dz_t[i] = wzv; }
  } else if (tid < 448) {
    const int l = tid - 384;
    float vv = SM_U12[l] * SM_Y[l] + SM_U12[l + 64] * SM_Y[l + 64];
    vv = wred_sum(vv);
    if (l == 0) {
      const float wyv = -(y1 + vv) * u11i;
      if (accum) sm.scal[dy_slot] += wyv; else sm.scal[dy_slot] = wyv;
      sm.scal[SC_WY] = wyv;
    }
  }
  __syncthreads();
  const float wy = sm.scal[SC_WY];
  {  // dx = Qinv g1, g1 inlined from partials (same summation order)
    float acc = 0.0f;
#pragma unroll
    for (int c = 0; c < 8; ++c) {
      const int j = seg * 8 + c;
      float g1v = sm.pool[GP_O + j] + sm.pool[GP_O + 64 + j] + sm.pool[GP_O + 128 + j]
                + sm.pool[GP_O + 192 + j] - Ab[j] * wy;
      if (has_rx) g1v -= rx[j];
      acc += qreg[c] * g1v;
    }
    acc += __shfl_down(acc, 4); acc += __shfl_down(acc, 2); acc += __shfl_down(acc, 1);
    if (seg == 0) { if (accum) dx_t[o8] += acc; else dx_t[o8] = acc; }
  }
  __syncthreads();
}

__global__ __launch_bounds__(NT, 6)
void optnet_kernel(const float* __restrict__ Qg, const float* __restrict__ pg,
                   const float* __restrict__ Ag, const float* __restrict__ bg,
                   const float* __restrict__ Gg, const float* __restrict__ hg,
                   float* __restrict__ outg) {
  __shared__ Smem sm;
  const int bId = blockIdx.x;
  const int tid = threadIdx.x;
  const float* Qb = Qg + (size_t)bId * 4096;
  const float* pb = pg + (size_t)bId * 64;
  const float* Ab = Ag + (size_t)bId * 64;
  const float  bb = bg[bId];
  const float* Gb = Gg + (size_t)bId * 8192;
  const float* hb = hg + (size_t)bId * 128;

  // ---- pre-factor Q: rank-8 chol + trtri at stride 68 -> V_Q (upper), zero lower
  for (int idx = tid; idx < 4096; idx += NT)
    sm.pool[(idx >> 6) * 68 + (idx & 63)] = Qb[idx];
  __syncthreads();
  {
    const int tr = tid >> 4, tc = tid & 15;
    const int i0 = tr << 2, j0 = tc << 3;
    const int act = (tr < 16) && (tc < 8);
    float Wq[4][8];
    if (act) {
#pragma unroll
      for (int m = 0; m < 4; ++m)
#pragma unroll
        for (int c = 0; c < 8; ++c)
          Wq[m][c] = sm.pool[(i0 + m) * 68 + j0 + c];
    }
    chol_rank8<64, 64, 68>(sm, sm.pool + QP_O, Wq, act, tid);
    write_U<68>(sm, Wq, act, i0, j0);
  }
  __syncthreads();
  trtri_fast<64, 68>(sm, sm.pool + QP_O, tid);
  for (int idx = tid; idx < 4096; idx += NT) {
    const int i = idx >> 6, j = idx & 63;
    if (i > j) sm.pool[i * 68 + j] = 0.0f;
  }
  __syncthreads();
  // ---- Qinv into registers: thread (o8=tid>>3) holds Qi[o8][8*seg .. +8)
  float qreg[8];
  {
    const int o = tid >> 3, sgq = tid & 7;
#pragma unroll 1
    for (int c = 0; c < 8; ++c) {
      const int j = sgq * 8 + c;
      float acc = 0.0f;
      for (int k = 0; k < 64; ++k) acc += sm.pool[o * 68 + k] * sm.pool[j * 68 + k];
      qreg[c] = acc;
    }
  }
  // ---- w = V_Q^T a (into t; overwrites the Q-path diag stash, now dead); u11
  if (tid < 64) {
    float acc = 0.0f;
    for (int m = 0; m < 64; ++m) acc += sm.pool[m * 68 + tid] * Ab[m];
    sm.t[tid] = acc;
  }
  __syncthreads();
  if (tid < 64) {
    float v = sm.t[tid] * sm.t[tid];
    v = wred_sum(v);
    if (tid == 0) sm.scal[SC_U11I] = 1.0f / sqrtf(v);
  }
  __syncthreads();
  // ---- t1 = V_Q^T G^T (64 x 128): V from LDS, G rows direct from global;
  // writes chunk jt at pch(jt) within each 128-float row
  {
    const int kt = tid & 15, jt = tid >> 4;
    const int k0 = kt << 2, j0 = jt << 2;
    const int woff = pch(jt) << 2;
    float t1a[4][4] = {};
#pragma unroll 1
    for (int m = 0; m < 64; m += 4) {
      const float4 g0 = *(const float4*)&Gb[(j0 + 0) * 64 + m];
      const float4 g1 = *(const float4*)&Gb[(j0 + 1) * 64 + m];
      const float4 g2 = *(const float4*)&Gb[(j0 + 2) * 64 + m];
      const float4 g3 = *(const float4*)&Gb[(j0 + 3) * 64 + m];
      const float gr[4][4] = {{g0.x, g0.y, g0.z, g0.w}, {g1.x, g1.y, g1.z, g1.w},
                              {g2.x, g2.y, g2.z, g2.w}, {g3.x, g3.y, g3.z, g3.w}};
#pragma unroll
      for (int i = 0; i < 4; ++i) {
        const float4 v = *(const float4*)&sm.pool[(m + i) * 68 + k0];
        const float vv[4] = {v.x, v.y, v.z, v.w};
#pragma unroll
        for (int a = 0; a < 4; ++a)
#pragma unroll
          for (int b2 = 0; b2 < 4; ++b2)
            t1a[a][b2] = fmaf(vv[a], gr[b2][i], t1a[a][b2]);
      }
    }
#pragma unroll
    for (int a = 0; a < 4; ++a)
      *(float4*)&sm.pool[T1_O + (k0 + a) * 128 + woff] =
          make_float4(t1a[a][0], t1a[a][1], t1a[a][2], t1a[a][3]);
  }
  __syncthreads();
  // ---- u12 partials (t1^T w, split-k over 4 groups; partials in dead V_Q)
  {
    const int o = tid & 127, p = tid >> 7;
    const int oc = o >> 2;
    const int ooff = (pch(oc) << 2) | (o & 3);  // permuted column position
    float acc = 0.0f;
    for (int k = (p << 4); k < (p << 4) + 16; ++k)
      acc += sm.pool[T1_O + k * 128 + ooff] * sm.t[k];
    sm.pool[(p << 7) + o] = acc;
  }
  __syncthreads();
  // FUSED: u12 combine (tid<128) | rz = -h (128..256) | dd = 1 (256..384)
  if (tid < 128) {
    SM_U12[tid] = (sm.pool[tid] + sm.pool[128 + tid] + sm.pool[256 + tid] + sm.pool[384 + tid])
                  * sm.scal[SC_U11I];
  } else if (tid < 256) {
    SM_RZ[tid - 128] = -hb[tid - 128];
  } else if (tid < 384) {
    SM_DD[tid - 256] = 1.0f;
  }
  __syncthreads();

  // ---- register-resident factor tile (lives across factor + both solves)
  float Wt[4][8];

  // ---- initial factor + solve (d = 1)
  rebuild_S(sm, Wt, 1, tid);
  sweep128(sm, Wt, tid);
  solve_kkt(sm, Wt, qreg, Gb, Ab, 1, pb, nullptr, 1, SM_RZ, -bb,
            SM_X, SM_S, SM_Z, SC_Y, 0, tid);
  // FUSED min+shift: wave 0 owns s, wave 1 owns z (in-wave broadcast)
  if (tid < 64) {
    float v = fminf(SM_S[tid], SM_S[tid + 64]);
    v = wred_min(v);
    v = __shfl(v, 0);
    const float cs = 1.0f - v;
    if (cs > 1.0f) { SM_S[tid] += cs; SM_S[tid + 64] += cs; }
  } else if (tid < 128) {
    const int l = tid - 64;
    float v = fminf(SM_Z[l], SM_Z[l + 64]);
    v = wred_min(v);
    v = __shfl(v, 0);
    const float cz = 1.0f - v;
    if (cz > 1.0f) { SM_Z[l] += cz; SM_Z[l + 64] += cz; }
  }
  __syncthreads();

  // ---- 5 IPM iterations
  for (int it = 0; it < 5; ++it) {
    if (tid < 256) {  // rx partials: G^T z + Q x (coalesced column reads)
      const int o = tid & 63, pq = tid >> 6;
      float acc = 0.0f;
      for (int i = (pq << 5); i < (pq << 5) + 32; ++i) acc += Gb[(i << 6) + o] * SM_Z[i];
      for (int k = (pq << 4); k < (pq << 4) + 16; ++k) acc += Qb[(k << 6) + o] * SM_X[k];
      sm.pool[GP_O + (pq << 6) + o] = acc;
    } else {  // rz = G x + s - h (coalesced row dots, 2-lane groups)
      const int l = tid - 256, i = l >> 1, q = l & 1;
      const float* gr = Gb + (i << 6) + (q << 5);
      float acc = 0.0f;
#pragma unroll
      for (int kk = 0; kk < 32; kk += 4) {
        const float4 g4 = *(const float4*)(gr + kk);
        const float4 x4 = *(const float4*)&SM_X[(q << 5) + kk];
        acc += g4.x * x4.x + g4.y * x4.y + g4.z * x4.z + g4.w * x4.w;
      }
      acc += __shfl_down(acc, 1);
      if (q == 0) SM_RZ[i] = acc + SM_S[i] - hb[i];
    }
    __syncthreads();
    // FUSED: rxv combine (wave 0) | ry (wave 1) | mu (wave 2) | dd (192..320)
    if (tid < 64) {
      SM_RXV[tid] = pb[tid] + Ab[tid] * sm.scal[SC_Y]
                  + sm.pool[GP_O + tid] + sm.pool[GP_O + 64 + tid]
                  + sm.pool[GP_O + 128 + tid] + sm.pool[GP_O + 192 + tid];
    } else if (tid < 128) {
      const int l = tid - 64;
      float v = Ab[l] * SM_X[l];
      v = wred_sum(v);
      if (l == 0) sm.scal[SC_RY] = v - bb;
    } else if (tid < 192) {
      const int l = tid - 128;
      float v = SM_S[l] * SM_Z[l] + SM_S[l + 64] * SM_Z[l + 64];
      v = wred_sum(v);
      if (l == 0) sm.scal[SC_MU] = v * (1.0f / 128.0f);
    } else if (tid < 320) {
      const int i = tid - 192;
      SM_DD[i] = SM_Z[i] / SM_S[i];
    }
    __syncthreads();
    rebuild_S(sm, Wt, 0, tid);
    sweep128(sm, Wt, tid);
    // affine predictor (rs = z)
    solve_kkt(sm, Wt, qreg, Gb, Ab, 1, SM_RXV, SM_Z, 1, SM_RZ, sm.scal[SC_RY],
              SM_DXA, SM_DSA, SM_DZA, SC_DYA, 0, tid);
    // FUSED alpha_aff + sigma (wave 0; alpha broadcast in-wave, not published)
    if (tid < 64) {
      float m = __builtin_inff();
#pragma unroll
      for (int rep = 0; rep < 2; ++rep) {
        const int i = tid + 64 * rep;
        m = fminf(m, step_val(SM_Z[i], SM_DZA[i]));
        m = fminf(m, step_val(SM_S[i], SM_DSA[i]));
      }
      m = wred_min(m);
      float alpha = 0.999f * fminf(m, 1.0f);
      alpha = __shfl(alpha, 0);
      float v = 0.0f;
#pragma unroll
      for (int rep = 0; rep < 2; ++rep) {
        const int i = tid + 64 * rep;
        v += (SM_S[i] + alpha * SM_DSA[i]) * (SM_Z[i] + alpha * SM_DZA[i]);
      }
      v = wred_sum(v);
      if (tid == 0) {
        const float mu = sm.scal[SC_MU];
        const float r = v / (mu * 128.0f);
        sm.scal[SC_MUSIG] = -mu * r * r * r;
      }
    }
    __syncthreads();
    // non_zero -> rz buffer (rs for corrector) + corrector H = rs/d, H1 = 0
    if (tid < 128) {
      const float v = (sm.scal[SC_MUSIG] + SM_DSA[tid] * SM_DZA[tid]) / SM_S[tid];
      SM_RZ[tid] = v;
      SM_H[tid] = v / SM_DD[tid];
    } else if (tid == 128) {
      sm.scal[SC_H1] = 0.0f;
    }
    __syncthreads();
    // corrector (light): accumulates into dxa/dsa/dza/SC_DYA
    solve_kkt(sm, Wt, qreg, Gb, Ab, 0, nullptr, SM_RZ, 0, nullptr, 0.0f,
              SM_DXA, SM_DSA, SM_DZA, SC_DYA, 1, tid);
    // FUSED alpha2 + state update (wave 0 does everything)
    if (tid < 64) {
      float m = __builtin_inff();
#pragma unroll
      for (int rep = 0; rep < 2; ++rep) {
        const int i = tid + 64 * rep;
        m = fminf(m, step_val(SM_Z[i], SM_DZA[i]));
        m = fminf(m, step_val(SM_S[i], SM_DSA[i]));
      }
      m = wred_min(m);
      float a2 = 0.999f * fminf(m, 1.0f);
      a2 = __shfl(a2, 0);
      SM_S[tid]      += a2 * SM_DSA[tid];
      SM_S[tid + 64] += a2 * SM_DSA[tid + 64];
      SM_Z[tid]      += a2 * SM_DZA[tid];
      SM_Z[tid + 64] += a2 * SM_DZA[tid + 64];
      SM_X[tid]      += a2 * SM_DXA[tid];
      if (tid == 0) sm.scal[SC_Y] += a2 * sm.scal[SC_DYA];
    }
    __syncthreads();
  }
  if (tid < 64) outg[((size_t)bId << 6) + tid] = SM_X[tid];
}

extern "C" void kernel_launch(void* const* d_in, const int* in_sizes, int n_in,
                              void* d_out, int out_size, void* d_ws, size_t ws_size,
                              hipStream_t stream) {
  (void)n_in; (void)d_ws; (void)ws_size; (void)out_size;
  const float* Q = (const float*)d_in[0];
  const float* p = (const float*)d_in[1];
  const float* A = (const float*)d_in[2];
  const float* b = (const float*)d_in[3];
  const float* G = (const float*)d_in[4];
  const float* h = (const float*)d_in[5];
  const int B = in_sizes[3];  // b has one element per batch
  optnet_kernel<<<B, NT, 0, stream>>>(Q, p, A, b, G, h, (float*)d_out);
}

// Round 8
// 1957.165 us; speedup vs baseline: 2.8354x; 2.8354x over previous
//
#include <hip/hip_runtime.h>
#include <math.h>

// OptNet batched QP IPM solver — Round 14: undo the R13 VGPR strangle.
// R13 (bounds(512,6)) forced VGPR 64->40, spilling the register-resident
// Wt tile: FETCH 1.1->4.5 GB, WRITE 0.5->9.9 GB, dur 1991->5549us. The
// occupancy goal was reached (59%, 3 blocks at 51200 B LDS) but via spills.
// Fix: __launch_bounds__(512,4) — a MINIMUM of 4 waves/SIMD; R12's identical
// structure compiled to 64 VGPR under it, and at 64 VGPR + 51200 B LDS the
// hardware can schedule 3 blocks/CU on its own (24 waves = 6/SIMD, 6x64=384
// <= 512 VGPR pool; 3x51200 = 153600 <= 160K LDS). Keeps R13's layout:
//  * t1 stride 128, all steady-state vectors in the dead V_Q region.
//  * pch(c)=((c&1)<<4)|(c>>1) chunk permutation on t1 + sweep panel rows:
//    16 tc-lanes span all 32 banks (2-way, free) — R13 measured conflicts
//    1.55e8 -> 5.4e7 with it.

#define NT 512
#define T1_O 4352    // t1 = V_Q^T G^T, 64 x 128 at stride 128, chunk-permuted
#define GP_O 2048    // g1 / rx split-k partials (256 floats)
#define QP_O 4352    // Q-path chol panel / trtri Vd scratch (pre-t1)

// steady-state vectors inside the dead V_Q region [2304, 3648)
#define SM_S   (sm.pool + 2304)
#define SM_Z   (sm.pool + 2432)
#define SM_RZ  (sm.pool + 2560)
#define SM_DSA (sm.pool + 2688)
#define SM_DZA (sm.pool + 2816)
#define SM_U12 (sm.pool + 2944)
#define SM_DD  (sm.pool + 3072)
#define SM_H   (sm.pool + 3200)
#define SM_Y   (sm.pool + 3328)
#define SM_X   (sm.pool + 3456)
#define SM_RXV (sm.pool + 3520)
#define SM_DXA (sm.pool + 3584)

struct __align__(16) Smem {
  float pool[12544];  // 50176 B: V_Q/panels/partials/vectors + t1
  float t[64];        // setup: Q-path diag stash, then w = V_Q^T a / Qinv rx
  float scalbuf[64];  // Q-path: [0,16) | sweep: [16,62)
  float scal[16];
};
static_assert(sizeof(Smem) <= 52000, "LDS must allow 3 blocks/CU");

enum { SC_H1 = 2, SC_U11I = 4, SC_RY = 5, SC_MU = 6,
       SC_MUSIG = 8, SC_Y = 9, SC_DYA = 10, SC_WY = 11 };

__device__ __forceinline__ float wred_sum(float v) {
#pragma unroll
  for (int off = 32; off > 0; off >>= 1) v += __shfl_down(v, off);
  return v;
}
__device__ __forceinline__ float wred_min(float v) {
#pragma unroll
  for (int off = 32; off > 0; off >>= 1) v = fminf(v, __shfl_down(v, off));
  return v;
}
__device__ __forceinline__ float step_val(float v, float dv) {
  float a = -v / dv;
  return (a > 0.0f) ? a : __builtin_inff();  // NaN -> inf (matches ref)
}
__device__ __forceinline__ constexpr int pk16(int i) {  // packed 16x16 upper row start
  return i * 16 - ((i * (i - 1)) >> 1);
}
// chunk permutation for 128-float rows: chunk c (float4 index, 0..31) stored
// at position pch(c). Bijective; lane tc's chunks {2tc,2tc+1} -> {tc, 16+tc}
// -> float offsets {4tc, 64+4tc}: 16 lanes cover all 32 banks (2-way).
__device__ __forceinline__ constexpr int pch(int c) {
  return ((c & 1) << 4) | (c >> 1);
}

// ======================= Q-path (64x64) machinery ==========================
// Panels/Vd at pool[QP_O..) (free until t1 exists). Diag stash in sm.t.

template<int RW>
__device__ __forceinline__ void elim_publish(Smem& sm, float* pan, float (&Wt)[4][8],
                                             int q, int tc) {
  const int tcd = q >> 1;
  const int co = (q & 1) << 2;
  float L10 = 0, L20 = 0, L30 = 0, L21 = 0, L31 = 0, L32 = 0;
  float id0 = 0, id1 = 0, id2 = 0, id3 = 0;
  if (tc == tcd) {
    float D[4][4];
#pragma unroll
    for (int m = 0; m < 4; ++m)
#pragma unroll
      for (int c = 0; c < 4; ++c) D[m][c] = Wt[m][co + c];
    id0 = 1.0f / D[0][0];
    L10 = D[0][1] * id0; L20 = D[0][2] * id0; L30 = D[0][3] * id0;
#pragma unroll
    for (int c = 0; c < 4; ++c) {
      D[1][c] -= L10 * D[0][c]; D[2][c] -= L20 * D[0][c]; D[3][c] -= L30 * D[0][c];
    }
    id1 = 1.0f / D[1][1];
    L21 = D[1][2] * id1; L31 = D[1][3] * id1;
#pragma unroll
    for (int c = 0; c < 4; ++c) { D[2][c] -= L21 * D[1][c]; D[3][c] -= L31 * D[1][c]; }
    id2 = 1.0f / D[2][2];
    L32 = D[2][3] * id2;
#pragma unroll
    for (int c = 0; c < 4; ++c) D[3][c] -= L32 * D[2][c];
    id3 = 1.0f / D[3][3];
  }
  const int src = ((q & 3) << 4) + tcd;
  L10 = __shfl(L10, src); L20 = __shfl(L20, src); L30 = __shfl(L30, src);
  L21 = __shfl(L21, src); L31 = __shfl(L31, src); L32 = __shfl(L32, src);
#pragma unroll
  for (int c = 0; c < 8; ++c) {
    Wt[1][c] = fmaf(-L10, Wt[0][c], Wt[1][c]);
    Wt[2][c] = fmaf(-L20, Wt[0][c], Wt[2][c]);
    Wt[2][c] = fmaf(-L21, Wt[1][c], Wt[2][c]);
    Wt[3][c] = fmaf(-L30, Wt[0][c], Wt[3][c]);
    Wt[3][c] = fmaf(-L31, Wt[1][c], Wt[3][c]);
    Wt[3][c] = fmaf(-L32, Wt[2][c], Wt[3][c]);
  }
  const int pb = (q >> 1) & 1;
  float* pp = pan + pb * (8 * RW) + (q & 1) * (4 * RW);
  const int j0 = tc << 3;
#pragma unroll
  for (int m = 0; m < 4; ++m) {
    *(float4*)&pp[m * RW + j0]     = make_float4(Wt[m][0], Wt[m][1], Wt[m][2], Wt[m][3]);
    *(float4*)&pp[m * RW + j0 + 4] = make_float4(Wt[m][4], Wt[m][5], Wt[m][6], Wt[m][7]);
  }
  if (tc == tcd) {
    float* sb = sm.scalbuf + pb * 8 + ((q & 1) << 2);
    sb[0] = id0; sb[1] = id1; sb[2] = id2; sb[3] = id3;
    sm.t[(q << 2) + 0] = id0; sm.t[(q << 2) + 1] = id1;  // diag stash (read by write_U)
    sm.t[(q << 2) + 2] = id2; sm.t[(q << 2) + 3] = id3;
  }
}

template<int RW>
__device__ __forceinline__ void apply_panel4(Smem& sm, float* pan, float (&Wt)[4][8],
                                             int pb, int half, int i0, int j0) {
  const float* pp = pan + pb * (8 * RW) + half * (4 * RW);
  const float* sb = sm.scalbuf + pb * 8 + (half << 2);
#pragma unroll 1
  for (int mm = 0; mm < 4; ++mm) {
    const float idm = sb[mm];
    const float4 pv  = *(const float4*)&pp[mm * RW + i0];
    const float4 pj0 = *(const float4*)&pp[mm * RW + j0];
    const float4 pj1 = *(const float4*)&pp[mm * RW + j0 + 4];
    const float um0 = pv.x * idm, um1 = pv.y * idm;
    const float um2 = pv.z * idm, um3 = pv.w * idm;
    const float pjv[8] = {pj0.x, pj0.y, pj0.z, pj0.w, pj1.x, pj1.y, pj1.z, pj1.w};
#pragma unroll
    for (int c = 0; c < 8; ++c) {
      Wt[0][c] = fmaf(-um0, pjv[c], Wt[0][c]);
      Wt[1][c] = fmaf(-um1, pjv[c], Wt[1][c]);
      Wt[2][c] = fmaf(-um2, pjv[c], Wt[2][c]);
      Wt[3][c] = fmaf(-um3, pjv[c], Wt[3][c]);
    }
  }
}

template<int N, int RW, int ST>
__device__ void chol_rank8(Smem& sm, float* pan, float (&Wt)[4][8], int act, int tid) {
  const int tr = tid >> 4, tc = tid & 15;
  const int i0 = tr << 2, j0 = tc << 3;
  constexpr int NP = N / 8;
#pragma unroll 1
  for (int P = 0; P < NP; ++P) {
    const int pb = P & 1;
    if (P > 0 && act && tr >= 2 * P) {
      apply_panel4<RW>(sm, pan, Wt, pb ^ 1, 0, i0, j0);
      apply_panel4<RW>(sm, pan, Wt, pb ^ 1, 1, i0, j0);
    }
    if ((tid >> 6) == (P >> 1)) {
      if (act && tr == 2 * P) elim_publish<RW>(sm, pan, Wt, 2 * P, tc);
      __threadfence_block();
      if (act && tr == 2 * P + 1) {
        apply_panel4<RW>(sm, pan, Wt, pb, 0, i0, j0);
        elim_publish<RW>(sm, pan, Wt, 2 * P + 1, tc);
      }
    }
    __syncthreads();
  }
}

template<int ST>
__device__ __forceinline__ void write_U(Smem& sm, float (&Wt)[4][8], int act,
                                        int i0, int j0) {
  if (act && j0 + 7 >= i0) {
    float sqv[4];
#pragma unroll
    for (int m = 0; m < 4; ++m) sqv[m] = sqrtf(sm.t[i0 + m]);  // diag stash
    if (j0 >= i0 + 3) {
#pragma unroll
      for (int m = 0; m < 4; ++m)
#pragma unroll
        for (int qq = 0; qq < 4; ++qq)
          *(float2*)&sm.pool[(i0 + m) * ST + j0 + 2 * qq] =
              make_float2(Wt[m][2 * qq] * sqv[m], Wt[m][2 * qq + 1] * sqv[m]);
    } else {
#pragma unroll
      for (int m = 0; m < 4; ++m) {
        const int i = i0 + m;
#pragma unroll
        for (int c = 0; c < 8; ++c) {
          const int j = j0 + c;
          if (j >= i) sm.pool[i * ST + j] = Wt[m][c] * sqv[m];
        }
      }
    }
  }
}

template<int N, int ST>
__device__ void trtri_fast(Smem& sm, float* vd, int tid) {
  constexpr int NB = N >> 4;
  if (tid < NB * 16) {
    const int blk = tid >> 4, c = tid & 15;
    const float* D = sm.pool + (blk << 4) * ST + (blk << 4);
    float vv[16];
#pragma unroll
    for (int i = 15; i >= 0; --i) {
      float acc = 0.0f;
      for (int k = i + 1; k < 16; ++k) acc += D[i * ST + k] * vv[k];
      const float di = D[i * ST + i];
      const float val = (i == c) ? (1.0f / di) : (-acc / di);
      vv[i] = (i <= c) ? val : 0.0f;
    }
#pragma unroll
    for (int i = 0; i < 16; ++i)
      if (i <= c) vd[blk * 136 + pk16(i) + (c - i)] = vv[i];
  }
  __syncthreads();
  constexpr int NROWS = 16 * (NB * (NB - 1) / 2);
  if (tid < NROWS) {
    int J = 1, base = 0;
    while (base + 16 * J <= tid) { base += 16 * J; ++J; }
    const int k = tid - base, Jb = J << 4;
    float u[16], o[16];
    float2* wr = (float2*)&sm.pool[k * ST + Jb];
#pragma unroll
    for (int q = 0; q < 8; ++q) { const float2 v = wr[q]; u[2*q] = v.x; u[2*q+1] = v.y; }
    const float* vdj = vd + J * 136;
#pragma unroll
    for (int c = 0; c < 16; ++c) {
      float acc = 0.0f;
#pragma unroll
      for (int jj = 0; jj <= c; ++jj) acc += u[jj] * vdj[pk16(jj) + (c - jj)];
      o[c] = acc;
    }
#pragma unroll
    for (int q = 0; q < 8; ++q) wr[q] = make_float2(o[2*q], o[2*q+1]);
  } else {
    for (int idx = tid - NROWS; idx < 256; idx += NT - NROWS) {
      const int r = idx >> 4, c2 = idx & 15;
      if (c2 >= r) sm.pool[r * ST + c2] = vd[pk16(r) + (c2 - r)];
    }
  }
  for (int J = 1; J < NB; ++J) {
    __syncthreads();
    const int Jb = J << 4;
    const int nStrip = Jb << 2;
    float acc[4] = {0.0f, 0.0f, 0.0f, 0.0f};
    int wi = 0, wc = 0;
    if (tid < nStrip) {
      wi = tid >> 2; wc = (tid & 3) << 2;
      for (int k = wi; k < Jb; ++k) {
        const float v = sm.pool[wi * ST + k];
        const float2 u0 = *(const float2*)&sm.pool[k * ST + Jb + wc];
        const float2 u1 = *(const float2*)&sm.pool[k * ST + Jb + wc + 2];
        acc[0] = fmaf(v, u0.x, acc[0]); acc[1] = fmaf(v, u0.y, acc[1]);
        acc[2] = fmaf(v, u1.x, acc[2]); acc[3] = fmaf(v, u1.y, acc[3]);
      }
      acc[0] = -acc[0]; acc[1] = -acc[1]; acc[2] = -acc[2]; acc[3] = -acc[3];
    } else if (tid < nStrip + 64) {
      const int l = tid - nStrip;
      const int r = l >> 2; wi = Jb + r; wc = (l & 3) << 2;
      const float* vp = vd + J * 136 + pk16(r) - r;
#pragma unroll
      for (int q = 0; q < 4; ++q) {
        const int c = wc + q;
        acc[q] = (c >= r) ? vp[c] : 0.0f;
      }
    }
    __syncthreads();
    if (tid < nStrip) {
      *(float2*)&sm.pool[wi * ST + Jb + wc]     = make_float2(acc[0], acc[1]);
      *(float2*)&sm.pool[wi * ST + Jb + wc + 2] = make_float2(acc[2], acc[3]);
    } else if (tid < nStrip + 64) {
      const int r = wi - Jb;
#pragma unroll
      for (int q = 0; q < 4; ++q)
        if (wc + q >= r) sm.pool[wi * ST + Jb + wc + q] = acc[q];
    }
  }
  __syncthreads();
}

// ======================= 128-factor: symmetric SWEEP (register-resident) ===
// Panels at pool[0,2048), rows chunk-permuted via pch(). After the sweep,
// Wt = -M^{-1} (full square tile per thread), never written to LDS.

__device__ __forceinline__ void elim_sweep(Smem& sm, float (&Wt)[4][8],
                                           int q, int tc) {
  const int tcd = q >> 1;
  const int co = (q & 1) << 2;
  float L10 = 0, L20 = 0, L30 = 0, L21 = 0, L31 = 0, L32 = 0;
  float id0 = 0, id1 = 0, id2 = 0, id3 = 0;
  if (tc == tcd) {
    float D[4][4];
#pragma unroll
    for (int m = 0; m < 4; ++m)
#pragma unroll
      for (int c = 0; c < 4; ++c) D[m][c] = Wt[m][co + c];
    id0 = 1.0f / D[0][0];
    L10 = D[0][1] * id0; L20 = D[0][2] * id0; L30 = D[0][3] * id0;
#pragma unroll
    for (int c = 0; c < 4; ++c) {
      D[1][c] -= L10 * D[0][c]; D[2][c] -= L20 * D[0][c]; D[3][c] -= L30 * D[0][c];
    }
    id1 = 1.0f / D[1][1];
    L21 = D[1][2] * id1; L31 = D[1][3] * id1;
#pragma unroll
    for (int c = 0; c < 4; ++c) { D[2][c] -= L21 * D[1][c]; D[3][c] -= L31 * D[1][c]; }
    id2 = 1.0f / D[2][2];
    L32 = D[2][3] * id2;
#pragma unroll
    for (int c = 0; c < 4; ++c) D[3][c] -= L32 * D[2][c];
    id3 = 1.0f / D[3][3];
  }
  const int src = ((q & 3) << 4) + tcd;
  L10 = __shfl(L10, src); L20 = __shfl(L20, src); L30 = __shfl(L30, src);
  L21 = __shfl(L21, src); L31 = __shfl(L31, src); L32 = __shfl(L32, src);
  id0 = __shfl(id0, src); id1 = __shfl(id1, src);
  id2 = __shfl(id2, src); id3 = __shfl(id3, src);
#pragma unroll
  for (int c = 0; c < 8; ++c) {  // own rows -> F_raw = L^{-1} * rows
    Wt[1][c] = fmaf(-L10, Wt[0][c], Wt[1][c]);
    Wt[2][c] = fmaf(-L20, Wt[0][c], Wt[2][c]);
    Wt[2][c] = fmaf(-L21, Wt[1][c], Wt[2][c]);
    Wt[3][c] = fmaf(-L30, Wt[0][c], Wt[3][c]);
    Wt[3][c] = fmaf(-L31, Wt[1][c], Wt[3][c]);
    Wt[3][c] = fmaf(-L32, Wt[2][c], Wt[3][c]);
  }
  const int pb = (q >> 1) & 1;
  float* pp = sm.pool + pb * 1024 + (q & 1) * 512;
  // publish F_raw: chunk 2tc -> pos tc*4, chunk 2tc+1 -> pos 64+tc*4 (pch)
  const int c0 = tc << 2;
#pragma unroll
  for (int m = 0; m < 4; ++m) {
    *(float4*)&pp[m * 128 + c0]      = make_float4(Wt[m][0], Wt[m][1], Wt[m][2], Wt[m][3]);
    *(float4*)&pp[m * 128 + 64 + c0] = make_float4(Wt[m][4], Wt[m][5], Wt[m][6], Wt[m][7]);
  }
  if (tc == tcd) {
    float* sb = sm.scalbuf + 16 + pb * 24 + (q & 1) * 12;
    sb[0] = id0; sb[1] = id1; sb[2] = id2; sb[3] = id3;
    sb[4] = L10; sb[5] = L20; sb[6] = L30; sb[7] = L21; sb[8] = L31; sb[9] = L32;
  }
  // own rows -> P^{-1}B = L^{-T} D^{-1} F (back-substitution, per column)
#pragma unroll
  for (int c = 0; c < 8; ++c) {
    const float t3 = id3 * Wt[3][c];
    const float t2 = id2 * Wt[2][c] - L32 * t3;
    const float t1v = id1 * Wt[1][c] - L21 * t2 - L31 * t3;
    const float t0 = id0 * Wt[0][c] - L10 * t1v - L20 * t2 - L30 * t3;
    Wt[0][c] = t0; Wt[1][c] = t1v; Wt[2][c] = t2; Wt[3][c] = t3;
  }
  if (tc == tcd) {  // pivot 4x4 <- -P^{-1} = -(L^{-1})^T D^{-1} L^{-1}
    const float m10 = -L10, m21 = -L21, m32 = -L32;
    const float m20 = -L20 + L21 * L10;
    const float m31 = -L31 + L32 * L21;
    const float m30 = -L30 + L31 * L10 + L32 * L20 - L32 * L21 * L10;
    const float P00 = id0 + id1*m10*m10 + id2*m20*m20 + id3*m30*m30;
    const float P01 = id1*m10 + id2*m20*m21 + id3*m30*m31;
    const float P02 = id2*m20 + id3*m30*m32;
    const float P03 = id3*m30;
    const float P11 = id1 + id2*m21*m21 + id3*m31*m31;
    const float P12 = id2*m21 + id3*m31*m32;
    const float P13 = id3*m31;
    const float P22 = id2 + id3*m32*m32;
    const float P23 = id3*m32;
    const float P33 = id3;
    Wt[0][co+0] = -P00; Wt[0][co+1] = -P01; Wt[0][co+2] = -P02; Wt[0][co+3] = -P03;
    Wt[1][co+0] = -P01; Wt[1][co+1] = -P11; Wt[1][co+2] = -P12; Wt[1][co+3] = -P13;
    Wt[2][co+0] = -P02; Wt[2][co+1] = -P12; Wt[2][co+2] = -P22; Wt[2][co+3] = -P23;
    Wt[3][co+0] = -P03; Wt[3][co+1] = -P13; Wt[3][co+2] = -P23; Wt[3][co+3] = -P33;
  }
}

__device__ __forceinline__ void apply_sweep(Smem& sm, float (&Wt)[4][8],
                                            int q, int i0, int j0, int tr, int tc,
                                            int skip_partner) {
  if (tr == q) return;  // own panel: rows already replaced at elim time
  if (skip_partner && !(q & 1) && tr == q + 1) return;
  const int pb = (q >> 1) & 1;
  const float* pp = sm.pool + pb * 1024 + (q & 1) * 512;
  const float* sb = sm.scalbuf + 16 + pb * 24 + (q & 1) * 12;
  const int c0 = tc << 2;                  // pch(2tc)*4
  const int pvo = pch(tr) << 2;            // chunk tr position (cols i0..i0+3)
#pragma unroll 1
  for (int mm = 0; mm < 4; ++mm) {
    const float idm = sb[mm];
    const float4 pv  = *(const float4*)&pp[mm * 128 + pvo];
    const float4 pj0 = *(const float4*)&pp[mm * 128 + c0];
    const float4 pj1 = *(const float4*)&pp[mm * 128 + 64 + c0];
    const float um0 = pv.x * idm, um1 = pv.y * idm;
    const float um2 = pv.z * idm, um3 = pv.w * idm;
    const float pjv[8] = {pj0.x, pj0.y, pj0.z, pj0.w, pj1.x, pj1.y, pj1.z, pj1.w};
#pragma unroll
    for (int c = 0; c < 8; ++c) {
      Wt[0][c] = fmaf(-um0, pjv[c], Wt[0][c]);
      Wt[1][c] = fmaf(-um1, pjv[c], Wt[1][c]);
      Wt[2][c] = fmaf(-um2, pjv[c], Wt[2][c]);
      Wt[3][c] = fmaf(-um3, pjv[c], Wt[3][c]);
    }
  }
  if (tc == (q >> 1)) {  // pivot-column cells: (P^{-1}B)[:, i] via back-sub
    const int co = (q & 1) << 2;
    const float id0 = sb[0], id1 = sb[1], id2 = sb[2], id3 = sb[3];
    const float L10 = sb[4], L20 = sb[5], L30 = sb[6];
    const float L21 = sb[7], L31 = sb[8], L32 = sb[9];
#pragma unroll
    for (int r = 0; r < 4; ++r) {
      const float f0 = pp[0 * 128 + pvo + r];
      const float f1 = pp[1 * 128 + pvo + r];
      const float f2 = pp[2 * 128 + pvo + r];
      const float f3 = pp[3 * 128 + pvo + r];
      const float t3 = id3 * f3;
      const float t2 = id2 * f2 - L32 * t3;
      const float t1v = id1 * f1 - L21 * t2 - L31 * t3;
      const float t0 = id0 * f0 - L10 * t1v - L20 * t2 - L30 * t3;
      Wt[r][co+0] = t0; Wt[r][co+1] = t1v; Wt[r][co+2] = t2; Wt[r][co+3] = t3;
    }
  }
}

__device__ void sweep128(Smem& sm, float (&Wt)[4][8], int tid) {
  const int tr = tid >> 4, tc = tid & 15;
  const int i0 = tr << 2, j0 = tc << 3;
#pragma unroll 1
  for (int P = 0; P < 16; ++P) {
    if (P > 0) {
      apply_sweep(sm, Wt, 2 * P - 2, i0, j0, tr, tc, 1);
      apply_sweep(sm, Wt, 2 * P - 1, i0, j0, tr, tc, 1);
    }
    if ((tid >> 6) == (P >> 1)) {
      if (tr == 2 * P) elim_sweep(sm, Wt, 2 * P, tc);
      __threadfence_block();
      if (tr == 2 * P + 1) {
        apply_sweep(sm, Wt, 2 * P, i0, j0, tr, tc, 0);
        elim_sweep(sm, Wt, 2 * P + 1, tc);
      }
    }
    __syncthreads();
  }
  apply_sweep(sm, Wt, 30, i0, j0, tr, tc, 1);
  apply_sweep(sm, Wt, 31, i0, j0, tr, tc, 1);
}

// ---- rebuild S = t1^T t1 - u12 u12^T + diag(d + eps) into registers.
// t1 rows are chunk-permuted; same fma order every factor. ----
__device__ void rebuild_S(Smem& sm, float (&Wt)[4][8], int init, int tid) {
  const int tr = tid >> 4, tc = tid & 15;
  const int i0 = tr << 2, j0 = tc << 3;
  const int c0 = tc << 2;          // pch(2tc)*4
  const int pvo = pch(tr) << 2;    // chunk tr position
#pragma unroll
  for (int m = 0; m < 4; ++m)
#pragma unroll
    for (int c = 0; c < 8; ++c) Wt[m][c] = 0.0f;
#pragma unroll 2
  for (int k = 0; k < 64; ++k) {
    const float* row = sm.pool + T1_O + k * 128;
    const float4 a  = *(const float4*)&row[pvo];
    const float4 b0 = *(const float4*)&row[c0];
    const float4 b1 = *(const float4*)&row[64 + c0];
    const float av[4] = {a.x, a.y, a.z, a.w};
    const float bv[8] = {b0.x, b0.y, b0.z, b0.w, b1.x, b1.y, b1.z, b1.w};
#pragma unroll
    for (int m = 0; m < 4; ++m)
#pragma unroll
      for (int c = 0; c < 8; ++c) Wt[m][c] = fmaf(av[m], bv[c], Wt[m][c]);
  }
#pragma unroll
  for (int m = 0; m < 4; ++m) {
    const float ui = SM_U12[i0 + m];
#pragma unroll
    for (int c = 0; c < 8; ++c) Wt[m][c] -= ui * SM_U12[j0 + c];
  }
#pragma unroll
  for (int m = 0; m < 4; ++m) {
    const int i = i0 + m;
    if (i >= j0 && i < j0 + 8) {
      const int c = i - j0;
      const float dval = init ? 1.0f : SM_S[i] / SM_Z[i];
      Wt[m][c] = Wt[m][c] + dval + 1e-6f;
    }
  }
}

// ---- KKT solve from register-resident -M^{-1} (Wt). has_rx=0 (corrector):
// t & H phases skipped — H, SC_H1 pre-filled by the caller. ----
__device__ void solve_kkt(Smem& sm, const float (&Wt)[4][8], const float* qreg,
                          const float* Gb, const float* Ab,
                          int has_rx, const float* rx, const float* rs,
                          int has_rz, const float* rz, float ry,
                          float* dx_t, float* ds_t, float* dz_t, int dy_slot,
                          int accum, int tid) {
  const float u11i = sm.scal[SC_U11I];
  const int o8 = tid >> 3, seg = tid & 7;
  const int tr = tid >> 4, tc = tid & 15;
  const int i0 = tr << 2, j0 = tc << 3;
  if (has_rx) {
    {  // t = Qinv rx via register Qi + 8-lane shfl reduce
      float acc = 0.0f;
#pragma unroll
      for (int c = 0; c < 8; ++c) acc += qreg[c] * rx[seg * 8 + c];
      acc += __shfl_down(acc, 4); acc += __shfl_down(acc, 2); acc += __shfl_down(acc, 1);
      if (seg == 0) sm.t[o8] = acc;
    }
    __syncthreads();
    {  // H = G t + rs/d - rz  (float4 row dots) + fused H1 = a.t - ry
      const int i = tid >> 2, q = tid & 3;
      float acc = 0.0f;
      const float* gr = Gb + (i << 6) + (q << 4);
#pragma unroll
      for (int kk = 0; kk < 16; kk += 4) {
        const float4 g4 = *(const float4*)(gr + kk);
        const float4 t4 = *(const float4*)&sm.t[(q << 4) + kk];
        acc += g4.x * t4.x + g4.y * t4.y + g4.z * t4.z + g4.w * t4.w;
      }
      float h1v = (tid < 64) ? Ab[tid] * sm.t[tid] : 0.0f;
      h1v = wred_sum(h1v);  // meaningful in wave 0 only
      acc += __shfl_down(acc, 2); acc += __shfl_down(acc, 1);
      if (q == 0) {
        if (rs) acc += rs[i] / SM_DD[i];
        if (has_rz) acc -= rz[i];
        SM_H[i] = acc;
      }
      if (tid == 0) sm.scal[SC_H1] = h1v - ry;
    }
    __syncthreads();
  }
  const float y1 = sm.scal[SC_H1] * u11i;
  {  // wz = Wt.(H - u12 y1), row-reduce over the 16-lane tc group -> Y
    float v[8];
#pragma unroll
    for (int c = 0; c < 8; ++c) v[c] = SM_H[j0 + c] - SM_U12[j0 + c] * y1;
#pragma unroll
    for (int m = 0; m < 4; ++m) {
      float p = 0.0f;
#pragma unroll
      for (int c = 0; c < 8; ++c) p = fmaf(Wt[m][c], v[c], p);
      p += __shfl_down(p, 8); p += __shfl_down(p, 4);
      p += __shfl_down(p, 2); p += __shfl_down(p, 1);
      if (tc == 0) SM_Y[i0 + m] = p;
    }
  }
  __syncthreads();
  // FUSED: g1 partials (tid<256) | ds,dz (256..384) | w_y (wave 6) — read Y
  if (tid < 256) {
    const int o = tid & 63, p = tid >> 6;
    float acc = 0.0f;
    for (int i = (p << 5); i < (p << 5) + 32; ++i)
      acc -= Gb[(i << 6) + o] * SM_Y[i];
    sm.pool[GP_O + (p << 6) + o] = acc;
  } else if (tid < 384) {
    const int i = tid - 256;
    const float wzv = SM_Y[i];
    const float r = rs ? rs[i] : 0.0f;
    const float dsv = (-r - wzv) / SM_DD[i];
    if (accum) { ds_t[i] += dsv; dz_t[i] += wzv; }
    else       { ds_t[i] = dsv;  dz_t[i] = wzv; }
  } else if (tid < 448) {
    const int l = tid - 384;
    float vv = SM_U12[l] * SM_Y[l] + SM_U12[l + 64] * SM_Y[l + 64];
    vv = wred_sum(vv);
    if (l == 0) {
      const float wyv = -(y1 + vv) * u11i;
      if (accum) sm.scal[dy_slot] += wyv; else sm.scal[dy_slot] = wyv;
      sm.scal[SC_WY] = wyv;
    }
  }
  __syncthreads();
  const float wy = sm.scal[SC_WY];
  {  // dx = Qinv g1, g1 inlined from partials (same summation order)
    float acc = 0.0f;
#pragma unroll
    for (int c = 0; c < 8; ++c) {
      const int j = seg * 8 + c;
      float g1v = sm.pool[GP_O + j] + sm.pool[GP_O + 64 + j] + sm.pool[GP_O + 128 + j]
                + sm.pool[GP_O + 192 + j] - Ab[j] * wy;
      if (has_rx) g1v -= rx[j];
      acc += qreg[c] * g1v;
    }
    acc += __shfl_down(acc, 4); acc += __shfl_down(acc, 2); acc += __shfl_down(acc, 1);
    if (seg == 0) { if (accum) dx_t[o8] += acc; else dx_t[o8] = acc; }
  }
  __syncthreads();
}

__global__ __launch_bounds__(NT, 4)
void optnet_kernel(const float* __restrict__ Qg, const float* __restrict__ pg,
                   const float* __restrict__ Ag, const float* __restrict__ bg,
                   const float* __restrict__ Gg, const float* __restrict__ hg,
                   float* __restrict__ outg) {
  __shared__ Smem sm;
  const int bId = blockIdx.x;
  const int tid = threadIdx.x;
  const float* Qb = Qg + (size_t)bId * 4096;
  const float* pb = pg + (size_t)bId * 64;
  const float* Ab = Ag + (size_t)bId * 64;
  const float  bb = bg[bId];
  const float* Gb = Gg + (size_t)bId * 8192;
  const float* hb = hg + (size_t)bId * 128;

  // ---- pre-factor Q: rank-8 chol + trtri at stride 68 -> V_Q (upper), zero lower
  for (int idx = tid; idx < 4096; idx += NT)
    sm.pool[(idx >> 6) * 68 + (idx & 63)] = Qb[idx];
  __syncthreads();
  {
    const int tr = tid >> 4, tc = tid & 15;
    const int i0 = tr << 2, j0 = tc << 3;
    const int act = (tr < 16) && (tc < 8);
    float Wq[4][8];
    if (act) {
#pragma unroll
      for (int m = 0; m < 4; ++m)
#pragma unroll
        for (int c = 0; c < 8; ++c)
          Wq[m][c] = sm.pool[(i0 + m) * 68 + j0 + c];
    }
    chol_rank8<64, 64, 68>(sm, sm.pool + QP_O, Wq, act, tid);
    write_U<68>(sm, Wq, act, i0, j0);
  }
  __syncthreads();
  trtri_fast<64, 68>(sm, sm.pool + QP_O, tid);
  for (int idx = tid; idx < 4096; idx += NT) {
    const int i = idx >> 6, j = idx & 63;
    if (i > j) sm.pool[i * 68 + j] = 0.0f;
  }
  __syncthreads();
  // ---- Qinv into registers: thread (o8=tid>>3) holds Qi[o8][8*seg .. +8)
  float qreg[8];
  {
    const int o = tid >> 3, sgq = tid & 7;
#pragma unroll 1
    for (int c = 0; c < 8; ++c) {
      const int j = sgq * 8 + c;
      float acc = 0.0f;
      for (int k = 0; k < 64; ++k) acc += sm.pool[o * 68 + k] * sm.pool[j * 68 + k];
      qreg[c] = acc;
    }
  }
  // ---- w = V_Q^T a (into t; overwrites the Q-path diag stash, now dead); u11
  if (tid < 64) {
    float acc = 0.0f;
    for (int m = 0; m < 64; ++m) acc += sm.pool[m * 68 + tid] * Ab[m];
    sm.t[tid] = acc;
  }
  __syncthreads();
  if (tid < 64) {
    float v = sm.t[tid] * sm.t[tid];
    v = wred_sum(v);
    if (tid == 0) sm.scal[SC_U11I] = 1.0f / sqrtf(v);
  }
  __syncthreads();
  // ---- t1 = V_Q^T G^T (64 x 128): V from LDS, G rows direct from global;
  // writes chunk jt at pch(jt) within each 128-float row
  {
    const int kt = tid & 15, jt = tid >> 4;
    const int k0 = kt << 2, j0 = jt << 2;
    const int woff = pch(jt) << 2;
    float t1a[4][4] = {};
#pragma unroll 1
    for (int m = 0; m < 64; m += 4) {
      const float4 g0 = *(const float4*)&Gb[(j0 + 0) * 64 + m];
      const float4 g1 = *(const float4*)&Gb[(j0 + 1) * 64 + m];
      const float4 g2 = *(const float4*)&Gb[(j0 + 2) * 64 + m];
      const float4 g3 = *(const float4*)&Gb[(j0 + 3) * 64 + m];
      const float gr[4][4] = {{g0.x, g0.y, g0.z, g0.w}, {g1.x, g1.y, g1.z, g1.w},
                              {g2.x, g2.y, g2.z, g2.w}, {g3.x, g3.y, g3.z, g3.w}};
#pragma unroll
      for (int i = 0; i < 4; ++i) {
        const float4 v = *(const float4*)&sm.pool[(m + i) * 68 + k0];
        const float vv[4] = {v.x, v.y, v.z, v.w};
#pragma unroll
        for (int a = 0; a < 4; ++a)
#pragma unroll
          for (int b2 = 0; b2 < 4; ++b2)
            t1a[a][b2] = fmaf(vv[a], gr[b2][i], t1a[a][b2]);
      }
    }
#pragma unroll
    for (int a = 0; a < 4; ++a)
      *(float4*)&sm.pool[T1_O + (k0 + a) * 128 + woff] =
          make_float4(t1a[a][0], t1a[a][1], t1a[a][2], t1a[a][3]);
  }
  __syncthreads();
  // ---- u12 partials (t1^T w, split-k over 4 groups; partials in dead V_Q)
  {
    const int o = tid & 127, p = tid >> 7;
    const int oc = o >> 2;
    const int ooff = (pch(oc) << 2) | (o & 3);  // permuted column position
    float acc = 0.0f;
    for (int k = (p << 4); k < (p << 4) + 16; ++k)
      acc += sm.pool[T1_O + k * 128 + ooff] * sm.t[k];
    sm.pool[(p << 7) + o] = acc;
  }
  __syncthreads();
  // FUSED: u12 combine (tid<128) | rz = -h (128..256) | dd = 1 (256..384)
  if (tid < 128) {
    SM_U12[tid] = (sm.pool[tid] + sm.pool[128 + tid] + sm.pool[256 + tid] + sm.pool[384 + tid])
                  * sm.scal[SC_U11I];
  } else if (tid < 256) {
    SM_RZ[tid - 128] = -hb[tid - 128];
  } else if (tid < 384) {
    SM_DD[tid - 256] = 1.0f;
  }
  __syncthreads();

  // ---- register-resident factor tile (lives across factor + both solves)
  float Wt[4][8];

  // ---- initial factor + solve (d = 1)
  rebuild_S(sm, Wt, 1, tid);
  sweep128(sm, Wt, tid);
  solve_kkt(sm, Wt, qreg, Gb, Ab, 1, pb, nullptr, 1, SM_RZ, -bb,
            SM_X, SM_S, SM_Z, SC_Y, 0, tid);
  // FUSED min+shift: wave 0 owns s, wave 1 owns z (in-wave broadcast)
  if (tid < 64) {
    float v = fminf(SM_S[tid], SM_S[tid + 64]);
    v = wred_min(v);
    v = __shfl(v, 0);
    const float cs = 1.0f - v;
    if (cs > 1.0f) { SM_S[tid] += cs; SM_S[tid + 64] += cs; }
  } else if (tid < 128) {
    const int l = tid - 64;
    float v = fminf(SM_Z[l], SM_Z[l + 64]);
    v = wred_min(v);
    v = __shfl(v, 0);
    const float cz = 1.0f - v;
    if (cz > 1.0f) { SM_Z[l] += cz; SM_Z[l + 64] += cz; }
  }
  __syncthreads();

  // ---- 5 IPM iterations
  for (int it = 0; it < 5; ++it) {
    if (tid < 256) {  // rx partials: G^T z + Q x (coalesced column reads)
      const int o = tid & 63, pq = tid >> 6;
      float acc = 0.0f;
      for (int i = (pq << 5); i < (pq << 5) + 32; ++i) acc += Gb[(i << 6) + o] * SM_Z[i];
      for (int k = (pq << 4); k < (pq << 4) + 16; ++k) acc += Qb[(k << 6) + o] * SM_X[k];
      sm.pool[GP_O + (pq << 6) + o] = acc;
    } else {  // rz = G x + s - h (coalesced row dots, 2-lane groups)
      const int l = tid - 256, i = l >> 1, q = l & 1;
      const float* gr = Gb + (i << 6) + (q << 5);
      float acc = 0.0f;
#pragma unroll
      for (int kk = 0; kk < 32; kk += 4) {
        const float4 g4 = *(const float4*)(gr + kk);
        const float4 x4 = *(const float4*)&SM_X[(q << 5) + kk];
        acc += g4.x * x4.x + g4.y * x4.y + g4.z * x4.z + g4.w * x4.w;
      }
      acc += __shfl_down(acc, 1);
      if (q == 0) SM_RZ[i] = acc + SM_S[i] - hb[i];
    }
    __syncthreads();
    // FUSED: rxv combine (wave 0) | ry (wave 1) | mu (wave 2) | dd (192..320)
    if (tid < 64) {
      SM_RXV[tid] = pb[tid] + Ab[tid] * sm.scal[SC_Y]
                  + sm.pool[GP_O + tid] + sm.pool[GP_O + 64 + tid]
                  + sm.pool[GP_O + 128 + tid] + sm.pool[GP_O + 192 + tid];
    } else if (tid < 128) {
      const int l = tid - 64;
      float v = Ab[l] * SM_X[l];
      v = wred_sum(v);
      if (l == 0) sm.scal[SC_RY] = v - bb;
    } else if (tid < 192) {
      const int l = tid - 128;
      float v = SM_S[l] * SM_Z[l] + SM_S[l + 64] * SM_Z[l + 64];
      v = wred_sum(v);
      if (l == 0) sm.scal[SC_MU] = v * (1.0f / 128.0f);
    } else if (tid < 320) {
      const int i = tid - 192;
      SM_DD[i] = SM_Z[i] / SM_S[i];
    }
    __syncthreads();
    rebuild_S(sm, Wt, 0, tid);
    sweep128(sm, Wt, tid);
    // affine predictor (rs = z)
    solve_kkt(sm, Wt, qreg, Gb, Ab, 1, SM_RXV, SM_Z, 1, SM_RZ, sm.scal[SC_RY],
              SM_DXA, SM_DSA, SM_DZA, SC_DYA, 0, tid);
    // FUSED alpha_aff + sigma (wave 0; alpha broadcast in-wave, not published)
    if (tid < 64) {
      float m = __builtin_inff();
#pragma unroll
      for (int rep = 0; rep < 2; ++rep) {
        const int i = tid + 64 * rep;
        m = fminf(m, step_val(SM_Z[i], SM_DZA[i]));
        m = fminf(m, step_val(SM_S[i], SM_DSA[i]));
      }
      m = wred_min(m);
      float alpha = 0.999f * fminf(m, 1.0f);
      alpha = __shfl(alpha, 0);
      float v = 0.0f;
#pragma unroll
      for (int rep = 0; rep < 2; ++rep) {
        const int i = tid + 64 * rep;
        v += (SM_S[i] + alpha * SM_DSA[i]) * (SM_Z[i] + alpha * SM_DZA[i]);
      }
      v = wred_sum(v);
      if (tid == 0) {
        const float mu = sm.scal[SC_MU];
        const float r = v / (mu * 128.0f);
        sm.scal[SC_MUSIG] = -mu * r * r * r;
      }
    }
    __syncthreads();
    // non_zero -> rz buffer (rs for corrector) + corrector H = rs/d, H1 = 0
    if (tid < 128) {
      const float v = (sm.scal[SC_MUSIG] + SM_DSA[tid] * SM_DZA[tid]) / SM_S[tid];
      SM_RZ[tid] = v;
      SM_H[tid] = v / SM_DD[tid];
    } else if (tid == 128) {
      sm.scal[SC_H1] = 0.0f;
    }
    __syncthreads();
    // corrector (light): accumulates into dxa/dsa/dza/SC_DYA
    solve_kkt(sm, Wt, qreg, Gb, Ab, 0, nullptr, SM_RZ, 0, nullptr, 0.0f,
              SM_DXA, SM_DSA, SM_DZA, SC_DYA, 1, tid);
    // FUSED alpha2 + state update (wave 0 does everything)
    if (tid < 64) {
      float m = __builtin_inff();
#pragma unroll
      for (int rep = 0; rep < 2; ++rep) {
        const int i = tid + 64 * rep;
        m = fminf(m, step_val(SM_Z[i], SM_DZA[i]));
        m = fminf(m, step_val(SM_S[i], SM_DSA[i]));
      }
      m = wred_min(m);
      float a2 = 0.999f * fminf(m, 1.0f);
      a2 = __shfl(a2, 0);
      SM_S[tid]      += a2 * SM_DSA[tid];
      SM_S[tid + 64] += a2 * SM_DSA[tid + 64];
      SM_Z[tid]      += a2 * SM_DZA[tid];
      SM_Z[tid + 64] += a2 * SM_DZA[tid + 64];
      SM_X[tid]      += a2 * SM_DXA[tid];
      if (tid == 0) sm.scal[SC_Y] += a2 * sm.scal[SC_DYA];
    }
    __syncthreads();
  }
  if (tid < 64) outg[((size_t)bId << 6) + tid] = SM_X[tid];
}

extern "C" void kernel_launch(void* const* d_in, const int* in_sizes, int n_in,
                              void* d_out, int out_size, void* d_ws, size_t ws_size,
                              hipStream_t stream) {
  (void)n_in; (void)d_ws; (void)ws_size; (void)out_size;
  const float* Q = (const float*)d_in[0];
  const float* p = (const float*)d_in[1];
  const float* A = (const float*)d_in[2];
  const float* b = (const float*)d_in[3];
  const float* G = (const float*)d_in[4];
  const float* h = (const float*)d_in[5];
  const int B = in_sizes[3];  // b has one element per batch
  optnet_kernel<<<B, NT, 0, stream>>>(Q, p, A, b, G, h, (float*)d_out);
}